// Round 1
// baseline (231.580 us; speedup 1.0000x reference)
//
#include <hip/hip_runtime.h>
#include <hip/hip_bf16.h>
#include <stdint.h>

#define D_MODEL 1024
#define NHEAD   16
#define HEAD_DIM 64
#define BATCH   2
#define SEQ     2048
#define M_TOK   (BATCH*SEQ)     // 4096
#define N_QKV   (3*D_MODEL)     // 3072
#define KDIM    1024
#define ATT_SCALE 0.125f        // 64^-0.5

typedef __bf16 bf16_t;
typedef bf16_t bf16x8 __attribute__((ext_vector_type(8)));
typedef bf16_t bf16x4 __attribute__((ext_vector_type(4)));
typedef float  f32x4  __attribute__((ext_vector_type(4)));

// async global->LDS, 16B per lane. lds base must be wave-uniform; HW writes
// base + lane*16B.
__device__ __forceinline__ void gl_lds16(const void* g, void* l) {
    __builtin_amdgcn_global_load_lds(
        (__attribute__((address_space(1))) void*)(void*)(const_cast<void*>(g)),
        (__attribute__((address_space(3))) void*)l, 16, 0, 0);
}

__global__ void convert_f32_bf16(const float* __restrict__ in,
                                 bf16_t* __restrict__ out, int n4) {
    int i = blockIdx.x * blockDim.x + threadIdx.x;
    if (i < n4) {
        float4 v = reinterpret_cast<const float4*>(in)[i];
        bf16x4 o = { (bf16_t)v.x, (bf16_t)v.y, (bf16_t)v.z, (bf16_t)v.w };
        reinterpret_cast<bf16x4*>(out)[i] = o;
    }
}

// C[m,n] = sum_k A[m,k]*B[n,k] (+bias). 128x128 tile, 4 waves (2x2 of 64x64),
// BK=32, 16x16x32 bf16 MFMA. m97 structure (2 barriers per K-step,
// global_load_lds width 16).
// MODE 0: qkv epilogue (bf16 out, Q scaled, V also scattered transposed)
// MODE 1: fp32 out + bias
template <int MODE>
__global__ __launch_bounds__(256) void gemm_bt(
    const bf16_t* __restrict__ A,    // [M][1024]
    const bf16_t* __restrict__ Bw,   // [N][1024]
    const float*  __restrict__ bias, // [N]
    int N,
    bf16_t* __restrict__ qkv_out,    // MODE 0: [M][3072]
    bf16_t* __restrict__ vt_out,     // MODE 0: [B*H*64][2048]
    float*  __restrict__ f32_out)    // MODE 1: [M][N]
{
    __shared__ bf16_t As[128 * 32];
    __shared__ bf16_t Bs[128 * 32];

    const int nbn = N / 128;
    const int bm = blockIdx.x / nbn;
    const int bn = blockIdx.x % nbn;
    const int m0 = bm * 128, n0 = bn * 128;
    const int tid = threadIdx.x, wave = tid >> 6, lane = tid & 63;
    const int wr = wave >> 1, wc = wave & 1;

    f32x4 acc[4][4] = {};

    // staging: per wave-call 16 rows x 32 cols (1024B). lane -> row lane>>2,
    // col (lane&3)*8, matching linear LDS fill.
    const int srow = lane >> 2;
    const int scol = (lane & 3) * 8;
    const bf16_t* gA0 = A  + (size_t)(m0 + wave * 16 + srow) * KDIM + scol;
    const bf16_t* gB0 = Bw + (size_t)(n0 + wave * 16 + srow) * KDIM + scol;
    bf16_t* lA0 = &As[(wave * 16) * 32];
    bf16_t* lB0 = &Bs[(wave * 16) * 32];

    for (int k0 = 0; k0 < KDIM; k0 += 32) {
        gl_lds16(gA0 + k0,             lA0);
        gl_lds16(gA0 + 64 * KDIM + k0, lA0 + 64 * 32);
        gl_lds16(gB0 + k0,             lB0);
        gl_lds16(gB0 + 64 * KDIM + k0, lB0 + 64 * 32);
        __syncthreads();

        const int ko = (lane >> 4) * 8;
        bf16x8 af[4], bfr[4];
#pragma unroll
        for (int i = 0; i < 4; i++)
            af[i] = *reinterpret_cast<const bf16x8*>(
                &As[(wr * 64 + i * 16 + (lane & 15)) * 32 + ko]);
#pragma unroll
        for (int j = 0; j < 4; j++)
            bfr[j] = *reinterpret_cast<const bf16x8*>(
                &Bs[(wc * 64 + j * 16 + (lane & 15)) * 32 + ko]);
#pragma unroll
        for (int i = 0; i < 4; i++)
#pragma unroll
            for (int j = 0; j < 4; j++)
                acc[i][j] = __builtin_amdgcn_mfma_f32_16x16x32_bf16(
                    af[i], bfr[j], acc[i][j], 0, 0, 0);
        __syncthreads();
    }

    // epilogue: C/D layout col=lane&15, row=(lane>>4)*4+reg  [verified m89/m91]
#pragma unroll
    for (int i = 0; i < 4; i++) {
#pragma unroll
        for (int j = 0; j < 4; j++) {
            const int col = n0 + wc * 64 + j * 16 + (lane & 15);
            const float bv = bias[col];
#pragma unroll
            for (int r = 0; r < 4; r++) {
                const int row = m0 + wr * 64 + i * 16 + (lane >> 4) * 4 + r;
                float v = acc[i][j][r] + bv;
                if (MODE == 0) {
                    const int s = col >> 10;
                    if (s == 0) {
                        qkv_out[(size_t)row * N_QKV + col] = (bf16_t)(v * ATT_SCALE);
                    } else if (s == 1) {
                        qkv_out[(size_t)row * N_QKV + col] = (bf16_t)v;
                    } else {
                        const int rem = col & 1023;
                        const int h = rem >> 6, d = rem & 63;
                        const int b = row >> 11, t = row & 2047;
                        vt_out[((size_t)((b * NHEAD + h) * HEAD_DIM + d)) * SEQ + t] =
                            (bf16_t)v;
                    }
                } else {
                    f32_out[(size_t)row * N + col] = v;
                }
            }
        }
    }
}

// Flash attention, causal. One block (4 waves) per 64-query tile per (b,h).
// Each wave owns 16 query rows. K tile [64 kv][64 d] and Vt tile [64 d][64 kv]
// staged in LDS; P transposed through per-wave LDS into MFMA A layout.
__global__ __launch_bounds__(256) void attn_fwd(
    const bf16_t* __restrict__ qkv,  // [4096][3072], Q pre-scaled
    const bf16_t* __restrict__ Vt,   // [(b*16+h)*64 + d][2048]
    bf16_t* __restrict__ O)          // [4096][1024]
{
    __shared__ bf16_t Ks[64 * 64];
    __shared__ bf16_t Vs[64 * 64];        // [d][kv]
    __shared__ bf16_t Ps[4][16 * 64];     // per-wave P [qrow][kv]

    const int nqt = SEQ / 64;             // 32
    const int bh = blockIdx.x / nqt;
    const int qt = blockIdx.x % nqt;
    const int b = bh >> 4, h = bh & 15;
    const int q0 = qt * 64;
    const int tid = threadIdx.x, wave = tid >> 6, lane = tid & 63;
    const int ko = (lane >> 4) * 8;

    // Q fragments (A operand): row = lane&15, k-chunk = (lane>>4)*8
    bf16x8 qf[2];
    {
        const size_t qrow = (size_t)(b * SEQ + q0 + wave * 16 + (lane & 15));
        const int cbase = h * 64 + ko;
        qf[0] = *reinterpret_cast<const bf16x8*>(&qkv[qrow * N_QKV + cbase]);
        qf[1] = *reinterpret_cast<const bf16x8*>(&qkv[qrow * N_QKV + cbase + 32]);
    }

    f32x4 acc_o[4] = {};
    float m_r[4], l_r[4];
#pragma unroll
    for (int r = 0; r < 4; r++) { m_r[r] = -1e30f; l_r[r] = 0.f; }

    const int srow = lane >> 3;          // 0..7
    const int scol = (lane & 7) * 8;     // 0..56
    const bf16_t* gK = qkv + (size_t)(b * SEQ) * N_QKV + (D_MODEL + h * 64);
    const bf16_t* gV = Vt + (size_t)(bh * 64) * SEQ;

    const int ntiles = qt + 1;
    for (int it = 0; it < ntiles; ++it) {
        const int kv0 = it * 64;
        // stage K rows / Vt rows: 8 rows of 128B per wave-call, 2 calls
#pragma unroll
        for (int c = 0; c < 2; c++) {
            const int row = c * 32 + wave * 8 + srow;
            gl_lds16(gK + (size_t)(kv0 + row) * N_QKV + scol,
                     &Ks[(c * 32 + wave * 8) * 64]);
            gl_lds16(gV + (size_t)row * SEQ + kv0 + scol,
                     &Vs[(c * 32 + wave * 8) * 64]);
        }
        __syncthreads();

        // S = Q K^T : s[j] covers kv cols j*16..+16 for this wave's 16 q rows
        f32x4 s[4];
#pragma unroll
        for (int j = 0; j < 4; j++) {
            bf16x8 k0f = *reinterpret_cast<const bf16x8*>(
                &Ks[(j * 16 + (lane & 15)) * 64 + ko]);
            bf16x8 k1f = *reinterpret_cast<const bf16x8*>(
                &Ks[(j * 16 + (lane & 15)) * 64 + 32 + ko]);
            f32x4 t = {0.f, 0.f, 0.f, 0.f};
            t = __builtin_amdgcn_mfma_f32_16x16x32_bf16(qf[0], k0f, t, 0, 0, 0);
            t = __builtin_amdgcn_mfma_f32_16x16x32_bf16(qf[1], k1f, t, 0, 0, 0);
            s[j] = t;
        }

        // causal mask (diagonal tile only: kv0 == q0)
        if (it == ntiles - 1) {
#pragma unroll
            for (int j = 0; j < 4; j++)
#pragma unroll
                for (int r = 0; r < 4; r++) {
                    const int qg = wave * 16 + (lane >> 4) * 4 + r;
                    const int kg = j * 16 + (lane & 15);
                    if (kg > qg) s[j][r] = -1e30f;
                }
        }

        // online softmax (rows replicated across 16-lane groups)
        float alpha[4];
#pragma unroll
        for (int r = 0; r < 4; r++) {
            float mx = fmaxf(fmaxf(s[0][r], s[1][r]), fmaxf(s[2][r], s[3][r]));
            mx = fmaxf(mx, __shfl_xor(mx, 1));
            mx = fmaxf(mx, __shfl_xor(mx, 2));
            mx = fmaxf(mx, __shfl_xor(mx, 4));
            mx = fmaxf(mx, __shfl_xor(mx, 8));
            const float mnew = fmaxf(m_r[r], mx);
            alpha[r] = __expf(m_r[r] - mnew);
            m_r[r] = mnew;
        }
        float rs[4] = {0.f, 0.f, 0.f, 0.f};
#pragma unroll
        for (int j = 0; j < 4; j++)
#pragma unroll
            for (int r = 0; r < 4; r++) {
                const float p = __expf(s[j][r] - m_r[r]);
                s[j][r] = p;
                rs[r] += p;
            }
#pragma unroll
        for (int r = 0; r < 4; r++) {
            rs[r] += __shfl_xor(rs[r], 1);
            rs[r] += __shfl_xor(rs[r], 2);
            rs[r] += __shfl_xor(rs[r], 4);
            rs[r] += __shfl_xor(rs[r], 8);
            l_r[r] = l_r[r] * alpha[r] + rs[r];
#pragma unroll
            for (int j = 0; j < 4; j++) acc_o[j][r] *= alpha[r];
        }

        // P -> LDS (C layout) -> A layout fragments
#pragma unroll
        for (int j = 0; j < 4; j++)
#pragma unroll
            for (int r = 0; r < 4; r++)
                Ps[wave][((lane >> 4) * 4 + r) * 64 + j * 16 + (lane & 15)] =
                    (bf16_t)s[j][r];

        bf16x8 pf0 = *reinterpret_cast<const bf16x8*>(
            &Ps[wave][(lane & 15) * 64 + ko]);
        bf16x8 pf1 = *reinterpret_cast<const bf16x8*>(
            &Ps[wave][(lane & 15) * 64 + 32 + ko]);

        // O += P V : B operand from Vs[d][kv] (contiguous along kv)
#pragma unroll
        for (int j = 0; j < 4; j++) {
            bf16x8 v0f = *reinterpret_cast<const bf16x8*>(
                &Vs[(j * 16 + (lane & 15)) * 64 + ko]);
            bf16x8 v1f = *reinterpret_cast<const bf16x8*>(
                &Vs[(j * 16 + (lane & 15)) * 64 + 32 + ko]);
            acc_o[j] = __builtin_amdgcn_mfma_f32_16x16x32_bf16(pf0, v0f, acc_o[j], 0, 0, 0);
            acc_o[j] = __builtin_amdgcn_mfma_f32_16x16x32_bf16(pf1, v1f, acc_o[j], 0, 0, 0);
        }
        __syncthreads();
    }

    // epilogue: O[row][h*64 + d] = acc / l
#pragma unroll
    for (int j = 0; j < 4; j++)
#pragma unroll
        for (int r = 0; r < 4; r++) {
            const size_t row =
                (size_t)(b * SEQ + q0 + wave * 16 + (lane >> 4) * 4 + r);
            const int col = h * 64 + j * 16 + (lane & 15);
            O[row * D_MODEL + col] = (bf16_t)(acc_o[j][r] / l_r[r]);
        }
}

extern "C" void kernel_launch(void* const* d_in, const int* in_sizes, int n_in,
                              void* d_out, int out_size, void* d_ws, size_t ws_size,
                              hipStream_t stream) {
    (void)in_sizes; (void)n_in; (void)out_size; (void)ws_size;
    const float* x    = (const float*)d_in[0];
    const float* Wqkv = (const float*)d_in[1];
    const float* bqkv = (const float*)d_in[2];
    const float* Wout = (const float*)d_in[3];
    const float* bout = (const float*)d_in[4];
    float* out = (float*)d_out;

    char* ws = (char*)d_ws;
    size_t off = 0;
    bf16_t* x_bf    = (bf16_t*)(ws + off); off += (size_t)M_TOK * KDIM * 2;        // 8 MB
    bf16_t* wqkv_bf = (bf16_t*)(ws + off); off += (size_t)N_QKV * KDIM * 2;        // 6 MB
    bf16_t* wout_bf = (bf16_t*)(ws + off); off += (size_t)D_MODEL * KDIM * 2;      // 2 MB
    bf16_t* qkv     = (bf16_t*)(ws + off); off += (size_t)M_TOK * N_QKV * 2;       // 24 MB
    bf16_t* vt      = (bf16_t*)(ws + off); off += (size_t)BATCH * NHEAD * HEAD_DIM * SEQ * 2; // 8 MB
    bf16_t* o_bf    = (bf16_t*)(ws + off); off += (size_t)M_TOK * D_MODEL * 2;     // 8 MB

    // fp32 -> bf16 converts
    {
        int n4 = M_TOK * KDIM / 4;
        convert_f32_bf16<<<(n4 + 255) / 256, 256, 0, stream>>>(x, x_bf, n4);
        n4 = N_QKV * KDIM / 4;
        convert_f32_bf16<<<(n4 + 255) / 256, 256, 0, stream>>>(Wqkv, wqkv_bf, n4);
        n4 = D_MODEL * KDIM / 4;
        convert_f32_bf16<<<(n4 + 255) / 256, 256, 0, stream>>>(Wout, wout_bf, n4);
    }

    // QKV projection: [4096][3072]
    gemm_bt<0><<<(M_TOK / 128) * (N_QKV / 128), 256, 0, stream>>>(
        x_bf, wqkv_bf, bqkv, N_QKV, qkv, vt, nullptr);

    // causal flash attention
    attn_fwd<<<BATCH * NHEAD * (SEQ / 64), 256, 0, stream>>>(qkv, vt, o_bf);

    // output projection: fp32 out
    gemm_bt<1><<<(M_TOK / 128) * (D_MODEL / 128), 256, 0, stream>>>(
        o_bf, wout_bf, bout, D_MODEL, nullptr, nullptr, out);
}

// Round 2
// 144.018 us; speedup vs baseline: 1.6080x; 1.6080x over previous
//
#include <hip/hip_runtime.h>
#include <hip/hip_bf16.h>
#include <stdint.h>

#define D_MODEL 1024
#define NHEAD   16
#define HEAD_DIM 64
#define BATCH   2
#define SEQ     2048
#define M_TOK   (BATCH*SEQ)     // 4096
#define N_QKV   (3*D_MODEL)     // 3072
#define KDIM    1024
#define ATT_SCALE 0.125f        // 64^-0.5

typedef __bf16 bf16_t;
typedef bf16_t bf16x8 __attribute__((ext_vector_type(8)));
typedef bf16_t bf16x4 __attribute__((ext_vector_type(4)));
typedef float  f32x4  __attribute__((ext_vector_type(4)));

// async global->LDS, 16B per lane. lds base must be wave-uniform; HW writes
// base + lane*16B.
__device__ __forceinline__ void gl_lds16(const void* g, void* l) {
    __builtin_amdgcn_global_load_lds(
        (__attribute__((address_space(1))) void*)(void*)(const_cast<void*>(g)),
        (__attribute__((address_space(3))) void*)l, 16, 0, 0);
}

__global__ void convert_f32_bf16(const float* __restrict__ in,
                                 bf16_t* __restrict__ out, int n4) {
    int i = blockIdx.x * blockDim.x + threadIdx.x;
    if (i < n4) {
        float4 v = reinterpret_cast<const float4*>(in)[i];
        bf16x4 o = { (bf16_t)v.x, (bf16_t)v.y, (bf16_t)v.z, (bf16_t)v.w };
        reinterpret_cast<bf16x4*>(out)[i] = o;
    }
}

// C[m,n] = sum_k A[m,k]*B[n,k] (+bias). 128x128 tile, 4 waves (2x2 of 64x64),
// BK=32, 16x16x32 bf16 MFMA. m97 structure + T2 LDS swizzle:
// LDS tile rows are 64B (4 x 16B chunks); chunk index XOR'd with (row>>1)&3
// on BOTH the (pre-swizzled) global staging source and the ds_read_b128,
// turning the 8-way fragment-read bank conflict into a free 2-way.
// MODE 0: qkv epilogue (bf16 out, Q scaled, V also scattered transposed)
// MODE 1: fp32 out + bias
template <int MODE>
__global__ __launch_bounds__(256) void gemm_bt(
    const bf16_t* __restrict__ A,    // [M][1024]
    const bf16_t* __restrict__ Bw,   // [N][1024]
    const float*  __restrict__ bias, // [N]
    int N,
    bf16_t* __restrict__ qkv_out,    // MODE 0: [M][3072]
    bf16_t* __restrict__ vt_out,     // MODE 0: [B*H*64][2048]
    float*  __restrict__ f32_out)    // MODE 1: [M][N]
{
    __shared__ bf16_t As[128 * 32];
    __shared__ bf16_t Bs[128 * 32];

    const int nbn = N / 128;
    const int bm = blockIdx.x / nbn;
    const int bn = blockIdx.x % nbn;
    const int m0 = bm * 128, n0 = bn * 128;
    const int tid = threadIdx.x, wave = tid >> 6, lane = tid & 63;
    const int wr = wave >> 1, wc = wave & 1;

    f32x4 acc[4][4] = {};

    // staging: per wave-call 16 rows x 32 cols (1024B). lane -> row lane>>2.
    // Source 16B-chunk pre-swizzled: chunk = (lane&3) ^ ((row>>1)&3), so
    // LDS[r][u] = G[r][u ^ ((r>>1)&3)] with a linear LDS fill.
    const int srow = lane >> 2;
    const int scol = ((lane & 3) ^ ((lane >> 3) & 3)) * 8;
    const bf16_t* gA0 = A  + (size_t)(m0 + wave * 16 + srow) * KDIM + scol;
    const bf16_t* gB0 = Bw + (size_t)(n0 + wave * 16 + srow) * KDIM + scol;
    bf16_t* lA0 = &As[(wave * 16) * 32];
    bf16_t* lB0 = &Bs[(wave * 16) * 32];

    const int fr = lane & 15;
    const int ch = ((lane >> 4) ^ ((fr >> 1) & 3)) * 8;  // swizzled chunk

    for (int k0 = 0; k0 < KDIM; k0 += 32) {
        gl_lds16(gA0 + k0,             lA0);
        gl_lds16(gA0 + 64 * KDIM + k0, lA0 + 64 * 32);
        gl_lds16(gB0 + k0,             lB0);
        gl_lds16(gB0 + 64 * KDIM + k0, lB0 + 64 * 32);
        __syncthreads();

        bf16x8 af[4], bfr[4];
#pragma unroll
        for (int i = 0; i < 4; i++)
            af[i] = *reinterpret_cast<const bf16x8*>(
                &As[(wr * 64 + i * 16 + fr) * 32 + ch]);
#pragma unroll
        for (int j = 0; j < 4; j++)
            bfr[j] = *reinterpret_cast<const bf16x8*>(
                &Bs[(wc * 64 + j * 16 + fr) * 32 + ch]);
#pragma unroll
        for (int i = 0; i < 4; i++)
#pragma unroll
            for (int j = 0; j < 4; j++)
                acc[i][j] = __builtin_amdgcn_mfma_f32_16x16x32_bf16(
                    af[i], bfr[j], acc[i][j], 0, 0, 0);
        __syncthreads();
    }

    // epilogue: C/D layout col=lane&15, row=(lane>>4)*4+reg  [verified m89/m91]
#pragma unroll
    for (int i = 0; i < 4; i++) {
#pragma unroll
        for (int j = 0; j < 4; j++) {
            const int col = n0 + wc * 64 + j * 16 + fr;
            const float bv = bias[col];
#pragma unroll
            for (int r = 0; r < 4; r++) {
                const int row = m0 + wr * 64 + i * 16 + (lane >> 4) * 4 + r;
                float v = acc[i][j][r] + bv;
                if (MODE == 0) {
                    const int s = col >> 10;
                    if (s == 0) {
                        qkv_out[(size_t)row * N_QKV + col] = (bf16_t)(v * ATT_SCALE);
                    } else if (s == 1) {
                        qkv_out[(size_t)row * N_QKV + col] = (bf16_t)v;
                    } else {
                        const int rem = col & 1023;
                        const int h = rem >> 6, d = rem & 63;
                        const int b = row >> 11, t = row & 2047;
                        vt_out[((size_t)((b * NHEAD + h) * HEAD_DIM + d)) * SEQ + t] =
                            (bf16_t)v;
                    }
                } else {
                    f32_out[(size_t)row * N + col] = v;
                }
            }
        }
    }
}

// Flash attention, causal. One block (4 waves) per 64-query tile per (b,h).
// Each wave owns 16 query rows. K tile [64 kv][64 d] and Vt tile [64 d][64 kv]
// staged in LDS with T2 XOR-swizzle (rows are 128B = 8 x 16B chunks;
// chunk ^= row&7 applied on the pre-swizzled global source AND the
// ds_read_b128 address — kills the 16-way bank conflict).
// P goes through per-wave LDS padded to 72 bf16/row (144B, 16B-aligned).
// Dispatch order is LPT: longest (qt=31) blocks first.
__global__ __launch_bounds__(256) void attn_fwd(
    const bf16_t* __restrict__ qkv,  // [4096][3072], Q pre-scaled
    const bf16_t* __restrict__ Vt,   // [(b*16+h)*64 + d][2048]
    bf16_t* __restrict__ O)          // [4096][1024]
{
    __shared__ bf16_t Ks[64 * 64];
    __shared__ bf16_t Vs[64 * 64];        // [d][kv]
    __shared__ bf16_t Ps[4][16 * 72];     // per-wave P [qrow][kv], padded

    const int nqt = SEQ / 64;             // 32
    const int nbh = BATCH * NHEAD;        // 32
    const int qt = (nqt - 1) - (blockIdx.x / nbh);  // LPT: long blocks first
    const int bh = blockIdx.x % nbh;
    const int b = bh >> 4, h = bh & 15;
    const int q0 = qt * 64;
    const int tid = threadIdx.x, wave = tid >> 6, lane = tid & 63;
    const int fr = lane & 15;             // fragment row within 16
    const int kq = lane >> 4;             // k-quarter 0..3
    const int sw = fr & 7;                // row-swizzle key for K/V reads
    const int c0 = (kq ^ sw) * 8;         // swizzled chunk, k 0..31
    const int c1 = ((kq + 4) ^ sw) * 8;   // swizzled chunk, k 32..63

    // Q fragments (A operand): row = lane&15, k-chunk = (lane>>4)*8
    bf16x8 qf[2];
    {
        const size_t qrow = (size_t)(b * SEQ + q0 + wave * 16 + fr);
        const int cbase = h * 64 + kq * 8;
        qf[0] = *reinterpret_cast<const bf16x8*>(&qkv[qrow * N_QKV + cbase]);
        qf[1] = *reinterpret_cast<const bf16x8*>(&qkv[qrow * N_QKV + cbase + 32]);
    }

    f32x4 acc_o[4] = {};
    float m_r[4], l_r[4];
#pragma unroll
    for (int r = 0; r < 4; r++) { m_r[r] = -1e30f; l_r[r] = 0.f; }

    // staging: lane -> row lane>>3 (of 8), source chunk pre-swizzled:
    // chunk = (lane&7) ^ row, so LDS[r][u] = G[r][u ^ (r&7)] (linear fill).
    const int srow = lane >> 3;
    const int scol = ((lane & 7) ^ srow) * 8;
    const bf16_t* gK = qkv + (size_t)(b * SEQ) * N_QKV + (D_MODEL + h * 64);
    const bf16_t* gV = Vt + (size_t)(bh * 64) * SEQ;

    const int ntiles = qt + 1;
    for (int it = 0; it < ntiles; ++it) {
        const int kv0 = it * 64;
        // stage K rows / Vt rows: 8 rows of 128B per wave-call, 2 calls
#pragma unroll
        for (int c = 0; c < 2; c++) {
            const int row = c * 32 + wave * 8 + srow;
            gl_lds16(gK + (size_t)(kv0 + row) * N_QKV + scol,
                     &Ks[(c * 32 + wave * 8) * 64]);
            gl_lds16(gV + (size_t)row * SEQ + kv0 + scol,
                     &Vs[(c * 32 + wave * 8) * 64]);
        }
        __syncthreads();

        // S = Q K^T : s[j] covers kv cols j*16..+16 for this wave's 16 q rows
        f32x4 s[4];
#pragma unroll
        for (int j = 0; j < 4; j++) {
            bf16x8 k0f = *reinterpret_cast<const bf16x8*>(
                &Ks[(j * 16 + fr) * 64 + c0]);
            bf16x8 k1f = *reinterpret_cast<const bf16x8*>(
                &Ks[(j * 16 + fr) * 64 + c1]);
            f32x4 t = {0.f, 0.f, 0.f, 0.f};
            t = __builtin_amdgcn_mfma_f32_16x16x32_bf16(qf[0], k0f, t, 0, 0, 0);
            t = __builtin_amdgcn_mfma_f32_16x16x32_bf16(qf[1], k1f, t, 0, 0, 0);
            s[j] = t;
        }

        // causal mask (diagonal tile only: kv0 == q0)
        if (it == ntiles - 1) {
#pragma unroll
            for (int j = 0; j < 4; j++)
#pragma unroll
                for (int r = 0; r < 4; r++) {
                    const int qg = wave * 16 + kq * 4 + r;
                    const int kg = j * 16 + fr;
                    if (kg > qg) s[j][r] = -1e30f;
                }
        }

        // online softmax (rows replicated across 16-lane groups)
        float alpha[4];
#pragma unroll
        for (int r = 0; r < 4; r++) {
            float mx = fmaxf(fmaxf(s[0][r], s[1][r]), fmaxf(s[2][r], s[3][r]));
            mx = fmaxf(mx, __shfl_xor(mx, 1));
            mx = fmaxf(mx, __shfl_xor(mx, 2));
            mx = fmaxf(mx, __shfl_xor(mx, 4));
            mx = fmaxf(mx, __shfl_xor(mx, 8));
            const float mnew = fmaxf(m_r[r], mx);
            alpha[r] = __expf(m_r[r] - mnew);
            m_r[r] = mnew;
        }
        float rs[4] = {0.f, 0.f, 0.f, 0.f};
#pragma unroll
        for (int j = 0; j < 4; j++)
#pragma unroll
            for (int r = 0; r < 4; r++) {
                const float p = __expf(s[j][r] - m_r[r]);
                s[j][r] = p;
                rs[r] += p;
            }
#pragma unroll
        for (int r = 0; r < 4; r++) {
            rs[r] += __shfl_xor(rs[r], 1);
            rs[r] += __shfl_xor(rs[r], 2);
            rs[r] += __shfl_xor(rs[r], 4);
            rs[r] += __shfl_xor(rs[r], 8);
            l_r[r] = l_r[r] * alpha[r] + rs[r];
#pragma unroll
            for (int j = 0; j < 4; j++) acc_o[j][r] *= alpha[r];
        }

        // P -> LDS (C layout, padded stride 72) -> A layout fragments
#pragma unroll
        for (int j = 0; j < 4; j++)
#pragma unroll
            for (int r = 0; r < 4; r++)
                Ps[wave][(kq * 4 + r) * 72 + j * 16 + fr] = (bf16_t)s[j][r];

        bf16x8 pf0 = *reinterpret_cast<const bf16x8*>(
            &Ps[wave][fr * 72 + kq * 8]);
        bf16x8 pf1 = *reinterpret_cast<const bf16x8*>(
            &Ps[wave][fr * 72 + 32 + kq * 8]);

        // O += P V : B operand from Vs[d][kv] (contiguous along kv, swizzled)
#pragma unroll
        for (int j = 0; j < 4; j++) {
            bf16x8 v0f = *reinterpret_cast<const bf16x8*>(
                &Vs[(j * 16 + fr) * 64 + c0]);
            bf16x8 v1f = *reinterpret_cast<const bf16x8*>(
                &Vs[(j * 16 + fr) * 64 + c1]);
            acc_o[j] = __builtin_amdgcn_mfma_f32_16x16x32_bf16(pf0, v0f, acc_o[j], 0, 0, 0);
            acc_o[j] = __builtin_amdgcn_mfma_f32_16x16x32_bf16(pf1, v1f, acc_o[j], 0, 0, 0);
        }
        __syncthreads();
    }

    // epilogue: O[row][h*64 + d] = acc / l
#pragma unroll
    for (int j = 0; j < 4; j++)
#pragma unroll
        for (int r = 0; r < 4; r++) {
            const size_t row =
                (size_t)(b * SEQ + q0 + wave * 16 + kq * 4 + r);
            const int col = h * 64 + j * 16 + fr;
            O[row * D_MODEL + col] = (bf16_t)(acc_o[j][r] / l_r[r]);
        }
}

extern "C" void kernel_launch(void* const* d_in, const int* in_sizes, int n_in,
                              void* d_out, int out_size, void* d_ws, size_t ws_size,
                              hipStream_t stream) {
    (void)in_sizes; (void)n_in; (void)out_size; (void)ws_size;
    const float* x    = (const float*)d_in[0];
    const float* Wqkv = (const float*)d_in[1];
    const float* bqkv = (const float*)d_in[2];
    const float* Wout = (const float*)d_in[3];
    const float* bout = (const float*)d_in[4];
    float* out = (float*)d_out;

    char* ws = (char*)d_ws;
    size_t off = 0;
    bf16_t* x_bf    = (bf16_t*)(ws + off); off += (size_t)M_TOK * KDIM * 2;        // 8 MB
    bf16_t* wqkv_bf = (bf16_t*)(ws + off); off += (size_t)N_QKV * KDIM * 2;        // 6 MB
    bf16_t* wout_bf = (bf16_t*)(ws + off); off += (size_t)D_MODEL * KDIM * 2;      // 2 MB
    bf16_t* qkv     = (bf16_t*)(ws + off); off += (size_t)M_TOK * N_QKV * 2;       // 24 MB
    bf16_t* vt      = (bf16_t*)(ws + off); off += (size_t)BATCH * NHEAD * HEAD_DIM * SEQ * 2; // 8 MB
    bf16_t* o_bf    = (bf16_t*)(ws + off); off += (size_t)M_TOK * D_MODEL * 2;     // 8 MB

    // fp32 -> bf16 converts
    {
        int n4 = M_TOK * KDIM / 4;
        convert_f32_bf16<<<(n4 + 255) / 256, 256, 0, stream>>>(x, x_bf, n4);
        n4 = N_QKV * KDIM / 4;
        convert_f32_bf16<<<(n4 + 255) / 256, 256, 0, stream>>>(Wqkv, wqkv_bf, n4);
        n4 = D_MODEL * KDIM / 4;
        convert_f32_bf16<<<(n4 + 255) / 256, 256, 0, stream>>>(Wout, wout_bf, n4);
    }

    // QKV projection: [4096][3072]
    gemm_bt<0><<<(M_TOK / 128) * (N_QKV / 128), 256, 0, stream>>>(
        x_bf, wqkv_bf, bqkv, N_QKV, qkv, vt, nullptr);

    // causal flash attention
    attn_fwd<<<BATCH * NHEAD * (SEQ / 64), 256, 0, stream>>>(qkv, vt, o_bf);

    // output projection: fp32 out
    gemm_bt<1><<<(M_TOK / 128) * (D_MODEL / 128), 256, 0, stream>>>(
        o_bf, wout_bf, bout, D_MODEL, nullptr, nullptr, out);
}